// Round 1
// baseline (463.708 us; speedup 1.0000x reference)
//
#include <hip/hip_runtime.h>
#include <cstdint>

// ---------------------------------------------------------------------------
// SarvamMoEAttention fused block for MI355X (gfx950).
// Pipeline: f32->bf16 conv | QKV GEMM (bf16 MFMA) | RMSNorm+RoPE | flash attn
//           (causal, GQA 16q/4kv, D=128) | out GEMM -> f32.
// Shapes: b=2, s=2048, h=2048, heads 16x128 (q) + 4x128 (k) + 4x128 (v).
// ---------------------------------------------------------------------------

#define DEVI __device__ __forceinline__

typedef float  f32x4  __attribute__((ext_vector_type(4)));
typedef float  f32x4v __attribute__((ext_vector_type(4)));
typedef __bf16 bf16x8 __attribute__((ext_vector_type(8)));
typedef __bf16 bf16x4 __attribute__((ext_vector_type(4)));

// async global->LDS, 16B per lane; LDS dest = wave-uniform base + lane*16.
DEVI void gload16(const void* g, void* l) {
  __builtin_amdgcn_global_load_lds(
      (const __attribute__((address_space(1))) void*)g,
      (__attribute__((address_space(3))) void*)l, 16, 0, 0);
}

// ---------------------------------------------------------------------------
// 1) fp32 -> bf16 elementwise conversion (vectorized float4 -> bf16x4)
// ---------------------------------------------------------------------------
__global__ __launch_bounds__(256) void cvt_bf16(const float* __restrict__ in,
                                                __bf16* __restrict__ out,
                                                long n) {
  long i = ((long)blockIdx.x * 256 + threadIdx.x) * 4;
  if (i >= n) return;
  f32x4 v = *(const f32x4*)(in + i);
  bf16x4 o;
  o[0] = (__bf16)v[0]; o[1] = (__bf16)v[1];
  o[2] = (__bf16)v[2]; o[3] = (__bf16)v[3];
  *(bf16x4*)(out + i) = o;
}

// ---------------------------------------------------------------------------
// 2/5) GEMM: C[M][N] = sum_k A[m][k] * B[n][k]   (A,B bf16 row-major, B^T form)
// 128x128 tile, BK=32, 4 waves (2x2 of 64x64), 16x16x32 bf16 MFMA.
// LDS staged via global_load_lds(16B) with chunk-XOR swizzle:
//   dest chunk (row,c) holds global chunk c ^ ((row>>1)&3)  [linear LDS dest,
//   pre-swizzled global source; ds_read applies the same XOR] -> 2-way banks.
// ---------------------------------------------------------------------------
template <typename CT>
__global__ __launch_bounds__(256) void gemm_bt(const __bf16* __restrict__ A,
                                               const __bf16* __restrict__ B,
                                               CT* __restrict__ C,
                                               int M, int N, int K) {
  __shared__ __bf16 As[4096];  // 128 rows x 32 cols
  __shared__ __bf16 Bs[4096];
  const int tid = threadIdx.x;
  const int l = tid & 63, w = tid >> 6;
  const int wr = w >> 1, wc = w & 1;
  const long rowBase = (long)blockIdx.y * 128;
  const long colBase = (long)blockIdx.x * 128;

  // staging: thread owns chunks {tid, 256+tid}; chunk=(row=idx>>2, c=idx&3)
  const int r0 = tid >> 2, c0 = tid & 3;
  const int cs0 = c0 ^ ((r0 >> 1) & 3);        // same for idx+256 (row+64)
  const __bf16* a0 = A + (rowBase + r0) * (long)K + cs0 * 8;
  const __bf16* a1 = A + (rowBase + r0 + 64) * (long)K + cs0 * 8;
  const __bf16* b0 = B + (colBase + r0) * (long)K + cs0 * 8;
  const __bf16* b1 = B + (colBase + r0 + 64) * (long)K + cs0 * 8;

  // fragment LDS byte offsets (fixed per lane across the K loop)
  const int axor = ((l & 15) >> 1) & 3;
  const int cofs = ((l >> 4) ^ axor) << 4;
  int aoff[4], boff[4];
#pragma unroll
  for (int m = 0; m < 4; ++m) aoff[m] = (wr * 64 + m * 16 + (l & 15)) * 64 + cofs;
#pragma unroll
  for (int n = 0; n < 4; ++n) boff[n] = (wc * 64 + n * 16 + (l & 15)) * 64 + cofs;

  f32x4 acc[4][4];
#pragma unroll
  for (int m = 0; m < 4; ++m)
#pragma unroll
    for (int n = 0; n < 4; ++n) acc[m][n] = f32x4{0.f, 0.f, 0.f, 0.f};

  const int nK = K >> 5;
  for (int kk = 0; kk < nK; ++kk) {
    __syncthreads();                       // prev compute done before overwrite
    gload16(a0, (char*)As + w * 1024);
    gload16(a1, (char*)As + 4096 + w * 1024);
    gload16(b0, (char*)Bs + w * 1024);
    gload16(b1, (char*)Bs + 4096 + w * 1024);
    a0 += 32; a1 += 32; b0 += 32; b1 += 32;
    __syncthreads();                       // staging drained (vmcnt at barrier)

    bf16x8 af[4], bfr[4];
#pragma unroll
    for (int m = 0; m < 4; ++m) af[m] = *(const bf16x8*)((const char*)As + aoff[m]);
#pragma unroll
    for (int n = 0; n < 4; ++n) bfr[n] = *(const bf16x8*)((const char*)Bs + boff[n]);
#pragma unroll
    for (int m = 0; m < 4; ++m)
#pragma unroll
      for (int n = 0; n < 4; ++n)
        acc[m][n] = __builtin_amdgcn_mfma_f32_16x16x32_bf16(af[m], bfr[n],
                                                            acc[m][n], 0, 0, 0);
  }

  // C write: C/D layout col=lane&15, row=4*(lane>>4)+r
  const long rb = rowBase + wr * 64 + ((l >> 4) << 2);
  const long cb = colBase + wc * 64 + (l & 15);
#pragma unroll
  for (int m = 0; m < 4; ++m)
#pragma unroll
    for (int n = 0; n < 4; ++n)
#pragma unroll
      for (int r = 0; r < 4; ++r)
        C[(rb + m * 16 + r) * (long)N + cb + n * 16] = (CT)acc[m][n][r];
}

// ---------------------------------------------------------------------------
// 3) RMSNorm + RoPE. One wave per (token, head-of-24). qkv bf16 [4096][3072].
// Q -> [b][16][s][128], K -> [b][4][s][128], V -> TRANSPOSED [b][4][128][s]
// (d-major V makes the attention PV B-operand a contiguous ds_read_b128).
// ---------------------------------------------------------------------------
__global__ __launch_bounds__(256) void normrope(
    const __bf16* __restrict__ qkv, const float* __restrict__ cosb,
    const float* __restrict__ sinb, const float* __restrict__ qw,
    const float* __restrict__ kw, __bf16* __restrict__ Qo,
    __bf16* __restrict__ Ko, __bf16* __restrict__ Vt) {
  const int tid = threadIdx.x, l = tid & 63, w = tid >> 6;
  const int pair = blockIdx.x * 4 + w;      // 98304 total
  const int t = pair / 24, hh = pair % 24;  // t = b*2048 + s
  const __bf16* src = qkv + (long)t * 3072 + hh * 128 + 2 * l;
  float x0 = (float)src[0], x1 = (float)src[1];

  if (hh < 20) {  // q and k heads: RMS norm + RoPE
    float ss = x0 * x0 + x1 * x1;
#pragma unroll
    for (int off = 1; off < 64; off <<= 1) ss += __shfl_xor(ss, off);
    const float rs = rsqrtf(ss * (1.0f / 128.0f) + 1e-6f);
    const float* wn = (hh < 16) ? qw : kw;
    x0 = x0 * rs * wn[2 * l];
    x1 = x1 * rs * wn[2 * l + 1];
    // rope on d<64; partner at d^32 lives on lane l^16
    float y0 = __shfl_xor(x0, 16);
    float y1 = __shfl_xor(x1, 16);
    if (l < 32) {
      float c0 = cosb[(long)t * 64 + 2 * l], c1 = cosb[(long)t * 64 + 2 * l + 1];
      float s0 = sinb[(long)t * 64 + 2 * l], s1 = sinb[(long)t * 64 + 2 * l + 1];
      if (l < 16) { x0 = x0 * c0 - y0 * s0; x1 = x1 * c1 - y1 * s1; }
      else        { x0 = x0 * c0 + y0 * s0; x1 = x1 * c1 + y1 * s1; }
    }
  }
  const int b = t >> 11, sIdx = t & 2047;
  if (hh < 16) {
    __bf16* dst = Qo + (((long)(b * 16 + hh)) * 2048 + sIdx) * 128 + 2 * l;
    dst[0] = (__bf16)x0; dst[1] = (__bf16)x1;
  } else if (hh < 20) {
    __bf16* dst = Ko + (((long)(b * 4 + hh - 16)) * 2048 + sIdx) * 128 + 2 * l;
    dst[0] = (__bf16)x0; dst[1] = (__bf16)x1;
  } else {
    __bf16* dst = Vt + (((long)(b * 4 + hh - 20)) * 128 + 2 * l) * 2048 + sIdx;
    dst[0] = (__bf16)x0; dst[2048] = (__bf16)x1;
  }
}

// ---------------------------------------------------------------------------
// 4) Flash attention, causal, GQA. Block = 4 waves, QBLK=64 (16 q-rows/wave),
// KBLK=64, D=128. K LDS [64][128] and Vt LDS [128][64], both XOR-swizzled
// ((row&7) on the 16B-chunk index) with pre-swizzled global_load_lds source.
// P transposed via per-wave swizzled LDS buffer.
// ---------------------------------------------------------------------------
__global__ __launch_bounds__(256) void attn_kernel(
    const __bf16* __restrict__ Q, const __bf16* __restrict__ Kg,
    const __bf16* __restrict__ Vg, __bf16* __restrict__ Aout) {
  __shared__ __bf16 Klds[8192];  // [64 kv][128 d], swizzled
  __shared__ __bf16 Vlds[8192];  // [128 d][64 kv], swizzled
  __shared__ __bf16 Plds[4096];  // per-wave [16 q][64 kv], swizzled
  const int tid = threadIdx.x, l = tid & 63, w = tid >> 6;
  const int qt = blockIdx.x, h = blockIdx.y, b = blockIdx.z;
  const int kvh = h >> 2;
  const int q0 = qt * 64;
  const int g = l >> 4, li = l & 15;

  // Q fragments in registers: row = q0 + w*16 + li, k-chunk = g*8
  const __bf16* Qp =
      Q + (((long)(b * 16 + h)) * 2048 + q0 + w * 16 + li) * 128 + g * 8;
  bf16x8 qf[4];
#pragma unroll
  for (int ks = 0; ks < 4; ++ks) qf[ks] = *(const bf16x8*)(Qp + ks * 32);

  const __bf16* Kp = Kg + ((long)(b * 4 + kvh)) * 2048 * 128;
  const __bf16* Vp = Vg + ((long)(b * 4 + kvh)) * 128 * 2048;  // d-major

  f32x4 o[8];
#pragma unroll
  for (int d = 0; d < 8; ++d) o[d] = f32x4{0.f, 0.f, 0.f, 0.f};
  float mrow[4], lrow[4];
#pragma unroll
  for (int r = 0; r < 4; ++r) { mrow[r] = -__builtin_inff(); lrow[r] = 0.f; }

  const int ntiles = qt + 1;  // causal: kv tiles 0..qt
  for (int kt = 0; kt < ntiles; ++kt) {
    const int kv0 = kt * 64;
    __syncthreads();  // all waves done reading LDS from prev tile
    // stage K [64][128]: chunk (row=ci>>4, c=ci&15), src chunk c^(row&7)
#pragma unroll
    for (int it = 0; it < 4; ++it) {
      int ci = it * 256 + tid;
      int row = ci >> 4, c = ci & 15;
      gload16(Kp + (long)(kv0 + row) * 128 + (c ^ (row & 7)) * 8,
              (char*)Klds + it * 4096 + w * 1024);
    }
    // stage Vt [128][64]: chunk (row=ci>>3, c=ci&7), src chunk c^(row&7)
#pragma unroll
    for (int it = 0; it < 4; ++it) {
      int ci = it * 256 + tid;
      int row = ci >> 3, c = ci & 7;
      gload16(Vp + (long)row * 2048 + kv0 + (c ^ (row & 7)) * 8,
              (char*)Vlds + it * 4096 + w * 1024);
    }
    __syncthreads();  // staging drained

    // --- QK^T: S[q16][kv64] per wave ---
    f32x4 s[4];
#pragma unroll
    for (int nf = 0; nf < 4; ++nf) s[nf] = f32x4{0.f, 0.f, 0.f, 0.f};
#pragma unroll
    for (int nf = 0; nf < 4; ++nf) {
      const char* kb = (const char*)Klds + (nf * 16 + li) * 256;
#pragma unroll
      for (int ks = 0; ks < 4; ++ks) {
        bf16x8 kf = *(const bf16x8*)(kb + ((((ks << 2) + g) ^ (l & 7)) << 4));
        s[nf] = __builtin_amdgcn_mfma_f32_16x16x32_bf16(qf[ks], kf, s[nf], 0, 0, 0);
      }
    }
    // scale + causal mask (rows q = q0 + w*16 + 4g + r)
    const int qg = q0 + w * 16 + (g << 2);
#pragma unroll
    for (int nf = 0; nf < 4; ++nf) {
      int kvg = kv0 + nf * 16 + li;
#pragma unroll
      for (int r = 0; r < 4; ++r) {
        float sv = s[nf][r] * 0.08838834764831845f;
        s[nf][r] = (kvg <= qg + r) ? sv : -__builtin_inff();
      }
    }
    // online softmax (row reduce over 16 lanes of the group)
    float mx[4], alpha[4];
#pragma unroll
    for (int r = 0; r < 4; ++r) {
      mx[r] = fmaxf(fmaxf(s[0][r], s[1][r]), fmaxf(s[2][r], s[3][r]));
      mx[r] = fmaxf(mx[r], __shfl_xor(mx[r], 1));
      mx[r] = fmaxf(mx[r], __shfl_xor(mx[r], 2));
      mx[r] = fmaxf(mx[r], __shfl_xor(mx[r], 4));
      mx[r] = fmaxf(mx[r], __shfl_xor(mx[r], 8));
      float mn = fmaxf(mrow[r], mx[r]);
      alpha[r] = __expf(mrow[r] - mn);
      mrow[r] = mn;
    }
    float rsum[4] = {0.f, 0.f, 0.f, 0.f};
#pragma unroll
    for (int nf = 0; nf < 4; ++nf)
#pragma unroll
      for (int r = 0; r < 4; ++r) {
        float p = __expf(s[nf][r] - mrow[r]);
        s[nf][r] = p;
        rsum[r] += p;
      }
#pragma unroll
    for (int r = 0; r < 4; ++r) {
      rsum[r] += __shfl_xor(rsum[r], 1);
      rsum[r] += __shfl_xor(rsum[r], 2);
      rsum[r] += __shfl_xor(rsum[r], 4);
      rsum[r] += __shfl_xor(rsum[r], 8);
      lrow[r] = lrow[r] * alpha[r] + rsum[r];
    }
#pragma unroll
    for (int d = 0; d < 8; ++d)
#pragma unroll
      for (int r = 0; r < 4; ++r) o[d][r] *= alpha[r];

    // write P (bf16) to per-wave swizzled LDS: byte = (qr*128+kv*2)^((qr&7)<<4)
    char* pw = (char*)Plds + w * 2048;
#pragma unroll
    for (int nf = 0; nf < 4; ++nf)
#pragma unroll
      for (int r = 0; r < 4; ++r) {
        int qr = (g << 2) + r;
        int off = (qr * 128 + (nf * 16 + li) * 2) ^ ((qr & 7) << 4);
        *(__bf16*)(pw + off) = (__bf16)s[nf][r];
      }

    // --- PV: O[q16][d128] += P[q16][kv] * V[kv][d] ---
#pragma unroll
    for (int kvs = 0; kvs < 2; ++kvs) {
      const bf16x8 pf = *(const bf16x8*)(
          (const char*)Plds + w * 2048 + li * 128 +
          ((((kvs << 2) + g) ^ (l & 7)) << 4));
#pragma unroll
      for (int d = 0; d < 8; ++d) {
        int dd = d * 16 + li;
        const bf16x8 vf = *(const bf16x8*)(
            (const char*)Vlds + dd * 128 + ((((kvs << 2) + g) ^ (li & 7)) << 4));
        o[d] = __builtin_amdgcn_mfma_f32_16x16x32_bf16(pf, vf, o[d], 0, 0, 0);
      }
    }
  }

  // epilogue: O /= l, write bf16 to attnout[b*s][h*128+d]
  __bf16* op = Aout + ((long)(b * 2048 + q0 + w * 16 + (g << 2))) * 2048 +
               h * 128 + li;
#pragma unroll
  for (int r = 0; r < 4; ++r) {
    float inv = 1.0f / lrow[r];
#pragma unroll
    for (int d = 0; d < 8; ++d)
      op[(long)r * 2048 + d * 16] = (__bf16)(o[d][r] * inv);
  }
}

// ---------------------------------------------------------------------------
// launch
// ---------------------------------------------------------------------------
extern "C" void kernel_launch(void* const* d_in, const int* in_sizes, int n_in,
                              void* d_out, int out_size, void* d_ws,
                              size_t ws_size, hipStream_t stream) {
  const float* hidden = (const float*)d_in[0];
  // d_in[1] = attention_mask (pure causal; implemented directly)
  const float* cosb = (const float*)d_in[2];
  const float* sinb = (const float*)d_in[3];
  const float* Wqkv = (const float*)d_in[4];
  const float* qw   = (const float*)d_in[5];
  const float* kw   = (const float*)d_in[6];
  const float* Wd   = (const float*)d_in[7];
  float* out = (float*)d_out;
  char* ws = (char*)d_ws;

  // phase-aliased workspace (total 62,914,560 B)
  __bf16* hb   = (__bf16*)(ws);                       // 16 MiB  (phase 1)
  __bf16* wqb  = (__bf16*)(ws + 16777216);            // 12 MiB  (phase 1)
  __bf16* Qb   = (__bf16*)(ws);                       // 16 MiB  (phase 2)
  __bf16* Kb   = (__bf16*)(ws + 16777216);            // 4 MiB   (phase 2)
  __bf16* Vb   = (__bf16*)(ws + 20971520);            // 4 MiB   (phase 2)
  __bf16* qkvb = (__bf16*)(ws + 29360128);            // 24 MiB  (phase 1)
  __bf16* aout = (__bf16*)(ws + 29360128);            // 16 MiB  (phase 2)
  __bf16* wdb  = (__bf16*)(ws + 54525952);            // 8 MiB

  // 1) conversions
  cvt_bf16<<<8192, 256, 0, stream>>>(hidden, hb, 8388608L);
  cvt_bf16<<<6144, 256, 0, stream>>>(Wqkv, wqb, 6291456L);
  cvt_bf16<<<4096, 256, 0, stream>>>(Wd, wdb, 4194304L);
  // 2) QKV GEMM: [4096 x 2048] * [3072 x 2048]^T -> bf16 [4096 x 3072]
  gemm_bt<__bf16><<<dim3(24, 32), 256, 0, stream>>>(hb, wqb, qkvb, 4096, 3072, 2048);
  // 3) RMSNorm + RoPE -> Q [b][16][s][128], K [b][4][s][128], V^T [b][4][128][s]
  normrope<<<24576, 256, 0, stream>>>(qkvb, cosb, sinb, qw, kw, Qb, Kb, Vb);
  // 4) flash attention -> bf16 [4096 x 2048]
  attn_kernel<<<dim3(32, 16, 2), 256, 0, stream>>>(Qb, Kb, Vb, aout);
  // 5) out GEMM: [4096 x 2048] * [2048 x 2048]^T -> f32 d_out
  gemm_bt<float><<<dim3(16, 32), 256, 0, stream>>>(aout, wdb, out, 4096, 2048, 2048);
}

// Round 3
// 383.094 us; speedup vs baseline: 1.2104x; 1.2104x over previous
//
#include <hip/hip_runtime.h>
#include <cstdint>

// ---------------------------------------------------------------------------
// SarvamMoEAttention fused block for MI355X (gfx950).
// Pipeline: f32->bf16 conv | QKV GEMM (bf16 MFMA) | RMSNorm+RoPE | flash attn
//           (causal, GQA 16q/4kv, D=128) | out GEMM -> f32.
// Shapes: b=2, s=2048, h=2048, heads 16x128 (q) + 4x128 (k) + 4x128 (v).
// R2: attn = paired q-tiles (p,31-p) for causal balance + dbuf K/V LDS with
//     raw s_barrier + counted vmcnt(8) (no vmcnt(0) drain in steady state),
//     setprio around MFMA clusters. GEMM: bijective XCD swizzle.
// (resubmission — R2 bench hit GPUAcquisitionTimeout, never ran)
// ---------------------------------------------------------------------------

#define DEVI __device__ __forceinline__

typedef float  f32x4  __attribute__((ext_vector_type(4)));
typedef __bf16 bf16x8 __attribute__((ext_vector_type(8)));
typedef __bf16 bf16x4 __attribute__((ext_vector_type(4)));

// async global->LDS, 16B per lane; LDS dest = wave-uniform base + lane*16.
DEVI void gload16(const void* g, void* l) {
  __builtin_amdgcn_global_load_lds(
      (const __attribute__((address_space(1))) void*)g,
      (__attribute__((address_space(3))) void*)l, 16, 0, 0);
}

// ---------------------------------------------------------------------------
// 1) fp32 -> bf16 elementwise conversion
// ---------------------------------------------------------------------------
__global__ __launch_bounds__(256) void cvt_bf16(const float* __restrict__ in,
                                                __bf16* __restrict__ out,
                                                long n) {
  long i = ((long)blockIdx.x * 256 + threadIdx.x) * 4;
  if (i >= n) return;
  f32x4 v = *(const f32x4*)(in + i);
  bf16x4 o;
  o[0] = (__bf16)v[0]; o[1] = (__bf16)v[1];
  o[2] = (__bf16)v[2]; o[3] = (__bf16)v[3];
  *(bf16x4*)(out + i) = o;
}

// ---------------------------------------------------------------------------
// 2/5) GEMM: C[M][N] = sum_k A[m][k] * B[n][k]   (bf16, B^T form)
// 128x128 tile, BK=32, 4 waves, 16x16x32 MFMA, chunk-XOR LDS swizzle,
// bijective XCD-aware block swizzle (requires nwg % 8 == 0).
// ---------------------------------------------------------------------------
template <typename CT>
__global__ __launch_bounds__(256) void gemm_bt(const __bf16* __restrict__ A,
                                               const __bf16* __restrict__ B,
                                               CT* __restrict__ C,
                                               int M, int N, int K) {
  __shared__ __bf16 As[4096];  // 128 rows x 32 cols
  __shared__ __bf16 Bs[4096];
  const int tid = threadIdx.x;
  const int l = tid & 63, w = tid >> 6;
  const int wr = w >> 1, wc = w & 1;

  // XCD swizzle: launch id orig -> work item swz (same XCD gets consecutive work)
  const int nbx = gridDim.x;
  const int nwg = nbx * gridDim.y;
  const int orig = blockIdx.y * nbx + blockIdx.x;
  const int swz = (orig & 7) * (nwg >> 3) + (orig >> 3);
  const int bx = swz % nbx, by = swz / nbx;

  const long rowBase = (long)by * 128;
  const long colBase = (long)bx * 128;

  // staging: thread owns chunks {tid, 256+tid}; chunk=(row=idx>>2, c=idx&3)
  const int r0 = tid >> 2, c0 = tid & 3;
  const int cs0 = c0 ^ ((r0 >> 1) & 3);
  const __bf16* a0 = A + (rowBase + r0) * (long)K + cs0 * 8;
  const __bf16* a1 = A + (rowBase + r0 + 64) * (long)K + cs0 * 8;
  const __bf16* b0 = B + (colBase + r0) * (long)K + cs0 * 8;
  const __bf16* b1 = B + (colBase + r0 + 64) * (long)K + cs0 * 8;

  const int axor = ((l & 15) >> 1) & 3;
  const int cofs = ((l >> 4) ^ axor) << 4;
  int aoff[4], boff[4];
#pragma unroll
  for (int m = 0; m < 4; ++m) aoff[m] = (wr * 64 + m * 16 + (l & 15)) * 64 + cofs;
#pragma unroll
  for (int n = 0; n < 4; ++n) boff[n] = (wc * 64 + n * 16 + (l & 15)) * 64 + cofs;

  f32x4 acc[4][4];
#pragma unroll
  for (int m = 0; m < 4; ++m)
#pragma unroll
    for (int n = 0; n < 4; ++n) acc[m][n] = f32x4{0.f, 0.f, 0.f, 0.f};

  const int nK = K >> 5;
  for (int kk = 0; kk < nK; ++kk) {
    __syncthreads();
    gload16(a0, (char*)As + w * 1024);
    gload16(a1, (char*)As + 4096 + w * 1024);
    gload16(b0, (char*)Bs + w * 1024);
    gload16(b1, (char*)Bs + 4096 + w * 1024);
    a0 += 32; a1 += 32; b0 += 32; b1 += 32;
    __syncthreads();

    bf16x8 af[4], bfr[4];
#pragma unroll
    for (int m = 0; m < 4; ++m) af[m] = *(const bf16x8*)((const char*)As + aoff[m]);
#pragma unroll
    for (int n = 0; n < 4; ++n) bfr[n] = *(const bf16x8*)((const char*)Bs + boff[n]);
#pragma unroll
    for (int m = 0; m < 4; ++m)
#pragma unroll
      for (int n = 0; n < 4; ++n)
        acc[m][n] = __builtin_amdgcn_mfma_f32_16x16x32_bf16(af[m], bfr[n],
                                                            acc[m][n], 0, 0, 0);
  }

  const long rb = rowBase + wr * 64 + ((l >> 4) << 2);
  const long cb = colBase + wc * 64 + (l & 15);
#pragma unroll
  for (int m = 0; m < 4; ++m)
#pragma unroll
    for (int n = 0; n < 4; ++n)
#pragma unroll
      for (int r = 0; r < 4; ++r)
        C[(rb + m * 16 + r) * (long)N + cb + n * 16] = (CT)acc[m][n][r];
}

// ---------------------------------------------------------------------------
// 3) RMSNorm + RoPE. One wave per (token, head-of-24). qkv bf16 [4096][3072].
// Q -> [b][16][s][128], K -> [b][4][s][128], V -> TRANSPOSED [b][4][128][s]
// ---------------------------------------------------------------------------
__global__ __launch_bounds__(256) void normrope(
    const __bf16* __restrict__ qkv, const float* __restrict__ cosb,
    const float* __restrict__ sinb, const float* __restrict__ qw,
    const float* __restrict__ kw, __bf16* __restrict__ Qo,
    __bf16* __restrict__ Ko, __bf16* __restrict__ Vt) {
  const int tid = threadIdx.x, l = tid & 63, w = tid >> 6;
  const int pair = blockIdx.x * 4 + w;
  const int t = pair / 24, hh = pair % 24;
  const __bf16* src = qkv + (long)t * 3072 + hh * 128 + 2 * l;
  float x0 = (float)src[0], x1 = (float)src[1];

  if (hh < 20) {
    float ss = x0 * x0 + x1 * x1;
#pragma unroll
    for (int off = 1; off < 64; off <<= 1) ss += __shfl_xor(ss, off);
    const float rs = rsqrtf(ss * (1.0f / 128.0f) + 1e-6f);
    const float* wn = (hh < 16) ? qw : kw;
    x0 = x0 * rs * wn[2 * l];
    x1 = x1 * rs * wn[2 * l + 1];
    float y0 = __shfl_xor(x0, 16);
    float y1 = __shfl_xor(x1, 16);
    if (l < 32) {
      float c0 = cosb[(long)t * 64 + 2 * l], c1 = cosb[(long)t * 64 + 2 * l + 1];
      float s0 = sinb[(long)t * 64 + 2 * l], s1 = sinb[(long)t * 64 + 2 * l + 1];
      if (l < 16) { x0 = x0 * c0 - y0 * s0; x1 = x1 * c1 - y1 * s1; }
      else        { x0 = x0 * c0 + y0 * s0; x1 = x1 * c1 + y1 * s1; }
    }
  }
  const int b = t >> 11, sIdx = t & 2047;
  if (hh < 16) {
    __bf16* dst = Qo + (((long)(b * 16 + hh)) * 2048 + sIdx) * 128 + 2 * l;
    dst[0] = (__bf16)x0; dst[1] = (__bf16)x1;
  } else if (hh < 20) {
    __bf16* dst = Ko + (((long)(b * 4 + hh - 16)) * 2048 + sIdx) * 128 + 2 * l;
    dst[0] = (__bf16)x0; dst[1] = (__bf16)x1;
  } else {
    __bf16* dst = Vt + (((long)(b * 4 + hh - 20)) * 128 + 2 * l) * 2048 + sIdx;
    dst[0] = (__bf16)x0; dst[2048] = (__bf16)x1;
  }
}

// ---------------------------------------------------------------------------
// 4) Flash attention, causal, GQA, paired q-tiles + dbuf pipeline.
// Block = 4 waves, QBLK=64 (16 q-rows/wave), KBLK=64, D=128.
// Block p handles q-tiles {p, 31-p} -> uniform 33 kv-tile iters per block.
// K/V double-buffered; per iter: barrier A (prev buf free) -> stage(t+1) ->
// vmcnt(8) (tile t landed) -> barrier B -> compute(t). Loads for t+1 stay in
// flight across compute(t).
// ---------------------------------------------------------------------------
DEVI void stage_kv(const __bf16* Kp, const __bf16* Vp, int kv0,
                   __bf16* Kl, __bf16* Vl, int tid, int w) {
#pragma unroll
  for (int it = 0; it < 4; ++it) {
    int ci = it * 256 + tid;
    int row = ci >> 4, c = ci & 15;
    gload16(Kp + (long)(kv0 + row) * 128 + (c ^ (row & 7)) * 8,
            (char*)Kl + it * 4096 + w * 1024);
  }
#pragma unroll
  for (int it = 0; it < 4; ++it) {
    int ci = it * 256 + tid;
    int row = ci >> 3, c = ci & 7;
    gload16(Vp + (long)row * 2048 + kv0 + (c ^ (row & 7)) * 8,
            (char*)Vl + it * 4096 + w * 1024);
  }
}

__global__ __launch_bounds__(256) void attn_kernel(
    const __bf16* __restrict__ Q, const __bf16* __restrict__ Kg,
    const __bf16* __restrict__ Vg, __bf16* __restrict__ Aout) {
  __shared__ __bf16 Klds[2][8192];  // [64 kv][128 d], swizzled, dbuf
  __shared__ __bf16 Vlds[2][8192];  // [128 d][64 kv], swizzled, dbuf
  __shared__ __bf16 Plds[4096];     // per-wave [16 q][64 kv], swizzled
  const int tid = threadIdx.x, l = tid & 63, w = tid >> 6;
  const int pr = blockIdx.x, h = blockIdx.y, b = blockIdx.z;
  const int kvh = h >> 2;
  const int g = l >> 4, li = l & 15;
  const __bf16* Kp = Kg + ((long)(b * 4 + kvh)) * 2048 * 128;
  const __bf16* Vp = Vg + ((long)(b * 4 + kvh)) * 128 * 2048;  // d-major

  for (int seg = 0; seg < 2; ++seg) {
    const int qt = seg ? (31 - pr) : pr;
    const int q0 = qt * 64;
    const int nt = qt + 1;

    // Q fragments: row = q0 + w*16 + li, k-chunk = g*8
    const __bf16* Qp =
        Q + (((long)(b * 16 + h)) * 2048 + q0 + w * 16 + li) * 128 + g * 8;
    bf16x8 qf[4];
#pragma unroll
    for (int ks = 0; ks < 4; ++ks) qf[ks] = *(const bf16x8*)(Qp + ks * 32);

    f32x4 o[8];
#pragma unroll
    for (int d = 0; d < 8; ++d) o[d] = f32x4{0.f, 0.f, 0.f, 0.f};
    float mrow[4], lrow[4];
#pragma unroll
    for (int r = 0; r < 4; ++r) { mrow[r] = -__builtin_inff(); lrow[r] = 0.f; }

    // all waves done reading LDS from previous segment before overwrite
    __builtin_amdgcn_s_barrier();
    stage_kv(Kp, Vp, 0, Klds[0], Vlds[0], tid, w);

    for (int kt = 0; kt < nt; ++kt) {
      const int cur = kt & 1;
      const int kv0 = kt * 64;
      __builtin_amdgcn_s_barrier();  // A: buf cur^1 free for overwrite
      if (kt + 1 < nt) {
        stage_kv(Kp, Vp, kv0 + 64, Klds[cur ^ 1], Vlds[cur ^ 1], tid, w);
        asm volatile("s_waitcnt vmcnt(8)" ::: "memory");  // tile kt landed
      } else {
        asm volatile("s_waitcnt vmcnt(0)" ::: "memory");
      }
      __builtin_amdgcn_s_barrier();  // B: tile kt visible to all waves
      __builtin_amdgcn_sched_barrier(0);

      const __bf16* Kl = Klds[cur];
      const __bf16* Vl = Vlds[cur];

      // --- QK^T: S[q16][kv64] per wave ---
      f32x4 s[4];
#pragma unroll
      for (int nf = 0; nf < 4; ++nf) s[nf] = f32x4{0.f, 0.f, 0.f, 0.f};
      __builtin_amdgcn_s_setprio(1);
#pragma unroll
      for (int nf = 0; nf < 4; ++nf) {
        const char* kb = (const char*)Kl + (nf * 16 + li) * 256;
#pragma unroll
        for (int ks = 0; ks < 4; ++ks) {
          bf16x8 kf = *(const bf16x8*)(kb + ((((ks << 2) + g) ^ (l & 7)) << 4));
          s[nf] = __builtin_amdgcn_mfma_f32_16x16x32_bf16(qf[ks], kf, s[nf], 0, 0, 0);
        }
      }
      __builtin_amdgcn_s_setprio(0);

      // scale + causal mask (rows q = q0 + w*16 + 4g + r)
      const int qg = q0 + w * 16 + (g << 2);
#pragma unroll
      for (int nf = 0; nf < 4; ++nf) {
        int kvg = kv0 + nf * 16 + li;
#pragma unroll
        for (int r = 0; r < 4; ++r) {
          float sv = s[nf][r] * 0.08838834764831845f;
          s[nf][r] = (kvg <= qg + r) ? sv : -__builtin_inff();
        }
      }
      // online softmax (row reduce over 16 lanes of the group)
      float mx[4], alpha[4];
#pragma unroll
      for (int r = 0; r < 4; ++r) {
        mx[r] = fmaxf(fmaxf(s[0][r], s[1][r]), fmaxf(s[2][r], s[3][r]));
        mx[r] = fmaxf(mx[r], __shfl_xor(mx[r], 1));
        mx[r] = fmaxf(mx[r], __shfl_xor(mx[r], 2));
        mx[r] = fmaxf(mx[r], __shfl_xor(mx[r], 4));
        mx[r] = fmaxf(mx[r], __shfl_xor(mx[r], 8));
        float mn = fmaxf(mrow[r], mx[r]);
        alpha[r] = __expf(mrow[r] - mn);
        mrow[r] = mn;
      }
      float rsum[4] = {0.f, 0.f, 0.f, 0.f};
#pragma unroll
      for (int nf = 0; nf < 4; ++nf)
#pragma unroll
        for (int r = 0; r < 4; ++r) {
          float p = __expf(s[nf][r] - mrow[r]);
          s[nf][r] = p;
          rsum[r] += p;
        }
#pragma unroll
      for (int r = 0; r < 4; ++r) {
        rsum[r] += __shfl_xor(rsum[r], 1);
        rsum[r] += __shfl_xor(rsum[r], 2);
        rsum[r] += __shfl_xor(rsum[r], 4);
        rsum[r] += __shfl_xor(rsum[r], 8);
        lrow[r] = lrow[r] * alpha[r] + rsum[r];
      }
#pragma unroll
      for (int d = 0; d < 8; ++d)
#pragma unroll
        for (int r = 0; r < 4; ++r) o[d][r] *= alpha[r];

      // write P (bf16) to per-wave swizzled LDS
      char* pw = (char*)Plds + w * 2048;
#pragma unroll
      for (int nf = 0; nf < 4; ++nf)
#pragma unroll
        for (int r = 0; r < 4; ++r) {
          int qr = (g << 2) + r;
          int off = (qr * 128 + (nf * 16 + li) * 2) ^ ((qr & 7) << 4);
          *(__bf16*)(pw + off) = (__bf16)s[nf][r];
        }

      // --- PV: O[q16][d128] += P[q16][kv] * V[kv][d] ---
      __builtin_amdgcn_s_setprio(1);
#pragma unroll
      for (int kvs = 0; kvs < 2; ++kvs) {
        const bf16x8 pf = *(const bf16x8*)(
            (const char*)Plds + w * 2048 + li * 128 +
            ((((kvs << 2) + g) ^ (l & 7)) << 4));
#pragma unroll
        for (int d = 0; d < 8; ++d) {
          int dd = d * 16 + li;
          const bf16x8 vf = *(const bf16x8*)(
              (const char*)Vl + dd * 128 + ((((kvs << 2) + g) ^ (li & 7)) << 4));
          o[d] = __builtin_amdgcn_mfma_f32_16x16x32_bf16(pf, vf, o[d], 0, 0, 0);
        }
      }
      __builtin_amdgcn_s_setprio(0);
    }

    // epilogue: O /= l, write bf16 to attnout[b*s][h*128+d]
    __bf16* op = Aout + ((long)(b * 2048 + q0 + w * 16 + (g << 2))) * 2048 +
                 h * 128 + li;
#pragma unroll
    for (int r = 0; r < 4; ++r) {
      float inv = 1.0f / lrow[r];
#pragma unroll
      for (int d = 0; d < 8; ++d)
        op[(long)r * 2048 + d * 16] = (__bf16)(o[d][r] * inv);
    }
  }
}

// ---------------------------------------------------------------------------
// launch
// ---------------------------------------------------------------------------
extern "C" void kernel_launch(void* const* d_in, const int* in_sizes, int n_in,
                              void* d_out, int out_size, void* d_ws,
                              size_t ws_size, hipStream_t stream) {
  const float* hidden = (const float*)d_in[0];
  const float* cosb = (const float*)d_in[2];
  const float* sinb = (const float*)d_in[3];
  const float* Wqkv = (const float*)d_in[4];
  const float* qw   = (const float*)d_in[5];
  const float* kw   = (const float*)d_in[6];
  const float* Wd   = (const float*)d_in[7];
  float* out = (float*)d_out;
  char* ws = (char*)d_ws;

  __bf16* hb   = (__bf16*)(ws);                       // 16 MiB  (phase 1)
  __bf16* wqb  = (__bf16*)(ws + 16777216);            // 12 MiB  (phase 1)
  __bf16* Qb   = (__bf16*)(ws);                       // 16 MiB  (phase 2)
  __bf16* Kb   = (__bf16*)(ws + 16777216);            // 4 MiB   (phase 2)
  __bf16* Vb   = (__bf16*)(ws + 20971520);            // 4 MiB   (phase 2)
  __bf16* qkvb = (__bf16*)(ws + 29360128);            // 24 MiB  (phase 1)
  __bf16* aout = (__bf16*)(ws + 29360128);            // 16 MiB  (phase 2)
  __bf16* wdb  = (__bf16*)(ws + 54525952);            // 8 MiB

  cvt_bf16<<<8192, 256, 0, stream>>>(hidden, hb, 8388608L);
  cvt_bf16<<<6144, 256, 0, stream>>>(Wqkv, wqb, 6291456L);
  cvt_bf16<<<4096, 256, 0, stream>>>(Wd, wdb, 4194304L);
  gemm_bt<__bf16><<<dim3(24, 32), 256, 0, stream>>>(hb, wqb, qkvb, 4096, 3072, 2048);
  normrope<<<24576, 256, 0, stream>>>(qkvb, cosb, sinb, qw, kw, Qb, Kb, Vb);
  attn_kernel<<<dim3(16, 16, 2), 256, 0, stream>>>(Qb, Kb, Vb, aout);
  gemm_bt<float><<<dim3(16, 32), 256, 0, stream>>>(aout, wdb, out, 4096, 2048, 2048);
}